// Round 3
// baseline (320.663 us; speedup 1.0000x reference)
//
#include <hip/hip_runtime.h>
#include <math.h>

#define B_ 64
#define I_ 4096
#define P_ 8      // Din
#define N_ 10
#define D_ 16
#define ND_ 160   // N*D
#define BND_ (B_*ND_)   // 10240
#define EPS_ 1e-7f

// Lane mapping: lane = g*16 + d, g = b-subgroup (0..3), d = output dim (0..15).
// Wave w covers b in {w*16 .. w*16+15} via 4 sub-iterations (bs).
// u_hat fragment tv[n] computed once per (b,i), used for logits (shfl-xor over
// the 16 d-lanes) and for the weighted accumulation.
// ipb is runtime: blocks = 4096/ipb. ipb=4 -> 1024 blocks = 4 blocks/CU = 4 waves/SIMD.
// LDS vsh is exactly 40960 B so 4 blocks/CU fit in the 160 KiB pool (no padding;
// the resulting 4-way g-conflict on Vc reads is 1.58x on a tiny fraction of ops).
template<int MODE>
__global__ __launch_bounds__(256, 4)
void digitcaps_pass(const float* __restrict__ x, const float* __restrict__ W,
                    const float* __restrict__ Vc, float* __restrict__ part,
                    int ipb)
{
    __shared__ float vsh[(MODE == 1) ? BND_ : 64];
    const int t = threadIdx.x;
    const int lane = t & 63;
    const int w = t >> 6;        // wave 0..3
    const int d = lane & 15;
    const int g = lane >> 4;     // 0..3

    if (MODE == 1) {
        // Vc natural layout [b][n][d] == vsh layout; straight coalesced copy.
        for (int k = t; k < BND_; k += 256) vsh[k] = Vc[k];
        __syncthreads();
    }

    float acc[4][N_];
#pragma unroll
    for (int bs = 0; bs < 4; ++bs)
#pragma unroll
        for (int n = 0; n < N_; ++n) acc[bs][n] = 0.f;

    const int i0 = blockIdx.x * ipb;

    for (int il = 0; il < ipb; ++il) {
        const int i = i0 + il;
        const float* __restrict__ Wi = W + (size_t)i * (N_ * P_ * D_) + d;

        float wr[N_ * P_];
#pragma unroll
        for (int n = 0; n < N_; ++n)
#pragma unroll
            for (int p = 0; p < P_; ++p)
                wr[n * P_ + p] = Wi[(n * P_ + p) * D_];   // 64B-contiguous per 16 lanes

#pragma unroll
        for (int bs = 0; bs < 4; ++bs) {
            const int b = w * 16 + bs * 4 + g;
            float xv[P_];
            {
                const float4* xp = (const float4*)(x + ((size_t)b * I_ + i) * P_);
                float4 a0 = xp[0], a1 = xp[1];
                xv[0]=a0.x; xv[1]=a0.y; xv[2]=a0.z; xv[3]=a0.w;
                xv[4]=a1.x; xv[5]=a1.y; xv[6]=a1.z; xv[7]=a1.w;
            }

            float tv[N_];   // u_hat[b,i,n,d] for this lane's d
#pragma unroll
            for (int n = 0; n < N_; ++n) {
                float s = 0.f;
#pragma unroll
                for (int p = 0; p < P_; ++p)
                    s = fmaf(xv[p], wr[n * P_ + p], s);
                tv[n] = s;
            }

            if (MODE == 0) {
                // c uniform (softmax of zeros) -> 0.1 scale applied in reduce
#pragma unroll
                for (int n = 0; n < N_; ++n) acc[bs][n] += tv[n];
            } else {
                float lg[N_];
#pragma unroll
                for (int n = 0; n < N_; ++n) {
                    float pr = tv[n] * vsh[b * ND_ + n * D_ + d];
                    pr += __shfl_xor(pr, 1);
                    pr += __shfl_xor(pr, 2);
                    pr += __shfl_xor(pr, 4);
                    pr += __shfl_xor(pr, 8);
                    lg[n] = pr;          // full dot over d, broadcast to 16-lane group
                }
                float m = lg[0];
#pragma unroll
                for (int n = 1; n < N_; ++n) m = fmaxf(m, lg[n]);
                float se = 0.f;
#pragma unroll
                for (int n = 0; n < N_; ++n) { lg[n] = __expf(lg[n] - m); se += lg[n]; }
                float inv = 1.f / se;
#pragma unroll
                for (int n = 0; n < N_; ++n)
                    acc[bs][n] = fmaf(lg[n] * inv, tv[n], acc[bs][n]);
            }
        }
    }

    // Each thread owns distinct (b,n,d) -> straight stores, no intra-block reduce.
    float* __restrict__ po = part + (size_t)blockIdx.x * BND_;
#pragma unroll
    for (int bs = 0; bs < 4; ++bs) {
        const int b = w * 16 + bs * 4 + g;
#pragma unroll
        for (int n = 0; n < N_; ++n)
            po[b * ND_ + n * D_ + d] = acc[bs][n];
    }
}

// Parallel-wide reduce: grid 640 x 256. Block handles 16 outputs k; 16 threads
// per k (tp) each sum rows/16 partials with coalesced loads (lanes 0..15 are
// consecutive k). Tree: shfl over tp within wave, LDS across waves.
__global__ __launch_bounds__(256)
void digitcaps_reduce(const float* __restrict__ part, int rows,
                      float scale, int mode,
                      float* __restrict__ Vc, float* __restrict__ out)
{
    __shared__ float sm[4][16];
    const int t = threadIdx.x;
    const int kk = t & 15;
    const int tp = t >> 4;                // 0..15
    const int k = blockIdx.x * 16 + kk;

    float s = 0.f;
    const int steps = rows >> 4;          // rows/16 per tp-thread
    const float* __restrict__ p0 = part + (size_t)tp * BND_ + k;
    const size_t stride = (size_t)16 * BND_;
#pragma unroll 8
    for (int j = 0; j < steps; ++j)
        s += p0[(size_t)j * stride];

    // reduce tp within wave: wave w holds tp in {4w..4w+3}
    s += __shfl_down(s, 32);
    s += __shfl_down(s, 16);
    if ((t & 63) < 16) sm[t >> 6][kk] = s;   // lane tp==4w writes wave-group sum
    __syncthreads();

    if (t < 16) {
        float tot = (sm[0][t] + sm[1][t]) + (sm[2][t] + sm[3][t]);
        tot *= scale;
        float sq = tot * tot;
        float v = tot * (sq / ((1.f + sq) * sqrtf(sq + EPS_)));
        int ko = blockIdx.x * 16 + t;         // = b*160 + n*16 + d natural layout
        if (mode == 0)      Vc[ko] = v;       // after iter 0: Vc = v0
        else if (mode == 1) Vc[ko] += v;      // after iter 1: Vc = v0 + v1
        else                out[ko] = v;      // final output [B,N,1,D]
    }
}

extern "C" void kernel_launch(void* const* d_in, const int* in_sizes, int n_in,
                              void* d_out, int out_size, void* d_ws, size_t ws_size,
                              hipStream_t stream)
{
    const float* x = (const float*)d_in[0];   // [64, 4096, 8] f32
    const float* W = (const float*)d_in[1];   // [4096, 10, 8, 16] f32
    float* out = (float*)d_out;               // [64, 10, 1, 16] f32

    // rows = #blocks in pass grid = partial width. Prefer 1024 (4 blocks/CU);
    // fall back to 512 (proven to fit in round 2) if ws is small.
    size_t need1024 = ((size_t)1024 * BND_ + BND_) * sizeof(float);
    int rows = (ws_size >= need1024) ? 1024 : 512;
    int ipb = I_ / rows;

    float* part = (float*)d_ws;
    float* Vc   = part + (size_t)rows * BND_;

    dim3 blk(256), grid(rows), rgrid(BND_ / 16);

    for (int pass = 0; pass < 3; ++pass) {
        if (pass == 0)
            digitcaps_pass<0><<<grid, blk, 0, stream>>>(x, W, nullptr, part, ipb);
        else
            digitcaps_pass<1><<<grid, blk, 0, stream>>>(x, W, Vc, part, ipb);
        digitcaps_reduce<<<rgrid, blk, 0, stream>>>(part, rows,
                                                    pass == 0 ? 0.1f : 1.0f, pass, Vc, out);
    }
}

// Round 4
// 224.832 us; speedup vs baseline: 1.4262x; 1.4262x over previous
//
#include <hip/hip_runtime.h>
#include <math.h>

#define B_ 64
#define I_ 4096
#define P_ 8      // Din
#define N_ 10
#define D_ 16
#define ND_ 160   // N*D
#define BND_ (B_*ND_)   // 10240
#define EPS_ 1e-7f

// Lane mapping: lane = g*16 + d, g = b-subgroup (0..3), d = output dim (0..15).
// Wave w covers b in {w*16 .. w*16+15} via 4 sub-iterations (bs).
// u_hat fragment tv[n] computed once per (b,i), reused for logits (shfl-xor
// over the 16 d-lanes) and the weighted accumulation.
//
// __launch_bounds__(256, 2): round 2 measured exactly 128 VGPR / no spill with
// this bound; round 3's (256,4) forced VGPR=64 -> 350 MB/pass scratch spill
// (FETCH 168 MB, WRITE 173 MB, HBM 50% peak). DO NOT tighten this bound.
// Occupancy comes from resources, not the bound: 128 VGPR -> 4 waves/SIMD,
// LDS 40960 B -> exactly 4 blocks/CU in the 160 KiB pool; grid 1024 fills it.
template<int MODE, int IPB>
__global__ __launch_bounds__(256, 2)
void digitcaps_pass(const float* __restrict__ x, const float* __restrict__ W,
                    const float* __restrict__ Vc, float* __restrict__ part)
{
    __shared__ float vsh[(MODE == 1) ? BND_ : 64];
    const int t = threadIdx.x;
    const int lane = t & 63;
    const int w = t >> 6;        // wave 0..3
    const int d = lane & 15;
    const int g = lane >> 4;     // 0..3

    if (MODE == 1) {
        // Vc natural layout [b][n][d] == vsh layout; straight coalesced copy.
        for (int k = t; k < BND_; k += 256) vsh[k] = Vc[k];
        __syncthreads();
    }

    float acc[4][N_];
#pragma unroll
    for (int bs = 0; bs < 4; ++bs)
#pragma unroll
        for (int n = 0; n < N_; ++n) acc[bs][n] = 0.f;

    const int i0 = blockIdx.x * IPB;

#pragma unroll
    for (int il = 0; il < IPB; ++il) {
        const int i = i0 + il;
        const float* __restrict__ Wi = W + (size_t)i * (N_ * P_ * D_) + d;

        float wr[N_ * P_];
#pragma unroll
        for (int n = 0; n < N_; ++n)
#pragma unroll
            for (int p = 0; p < P_; ++p)
                wr[n * P_ + p] = Wi[(n * P_ + p) * D_];   // 64B-contiguous per 16 lanes

#pragma unroll
        for (int bs = 0; bs < 4; ++bs) {
            const int b = w * 16 + bs * 4 + g;
            float xv[P_];
            {
                const float4* xp = (const float4*)(x + ((size_t)b * I_ + i) * P_);
                float4 a0 = xp[0], a1 = xp[1];
                xv[0]=a0.x; xv[1]=a0.y; xv[2]=a0.z; xv[3]=a0.w;
                xv[4]=a1.x; xv[5]=a1.y; xv[6]=a1.z; xv[7]=a1.w;
            }

            float tv[N_];   // u_hat[b,i,n,d] for this lane's d
#pragma unroll
            for (int n = 0; n < N_; ++n) {
                float s = 0.f;
#pragma unroll
                for (int p = 0; p < P_; ++p)
                    s = fmaf(xv[p], wr[n * P_ + p], s);
                tv[n] = s;
            }

            if (MODE == 0) {
                // c uniform (softmax of zeros) -> 0.1 scale applied in reduce
#pragma unroll
                for (int n = 0; n < N_; ++n) acc[bs][n] += tv[n];
            } else {
                float lg[N_];
#pragma unroll
                for (int n = 0; n < N_; ++n) {
                    float pr = tv[n] * vsh[b * ND_ + n * D_ + d];
                    pr += __shfl_xor(pr, 1);
                    pr += __shfl_xor(pr, 2);
                    pr += __shfl_xor(pr, 4);
                    pr += __shfl_xor(pr, 8);
                    lg[n] = pr;          // full dot over d, broadcast to 16-lane group
                }
                float m = lg[0];
#pragma unroll
                for (int n = 1; n < N_; ++n) m = fmaxf(m, lg[n]);
                float se = 0.f;
#pragma unroll
                for (int n = 0; n < N_; ++n) { lg[n] = __expf(lg[n] - m); se += lg[n]; }
                float inv = 1.f / se;
#pragma unroll
                for (int n = 0; n < N_; ++n)
                    acc[bs][n] = fmaf(lg[n] * inv, tv[n], acc[bs][n]);
            }
        }
    }

    // Each thread owns distinct (b,n,d) -> straight stores, no intra-block reduce.
    float* __restrict__ po = part + (size_t)blockIdx.x * BND_;
#pragma unroll
    for (int bs = 0; bs < 4; ++bs) {
        const int b = w * 16 + bs * 4 + g;
#pragma unroll
        for (int n = 0; n < N_; ++n)
            po[b * ND_ + n * D_ + d] = acc[bs][n];
    }
}

// Parallel-wide reduce: grid 640 x 256. Block handles 16 outputs k; 16 threads
// per k (tp) each sum rows/16 partials with coalesced loads (lanes 0..15 are
// consecutive k). Tree: shfl over tp within wave, LDS across waves.
__global__ __launch_bounds__(256)
void digitcaps_reduce(const float* __restrict__ part, int rows,
                      float scale, int mode,
                      float* __restrict__ Vc, float* __restrict__ out)
{
    __shared__ float sm[4][16];
    const int t = threadIdx.x;
    const int kk = t & 15;
    const int tp = t >> 4;                // 0..15
    const int k = blockIdx.x * 16 + kk;

    float s = 0.f;
    const int steps = rows >> 4;          // rows/16 per tp-thread
    const float* __restrict__ p0 = part + (size_t)tp * BND_ + k;
    const size_t stride = (size_t)16 * BND_;
#pragma unroll 8
    for (int j = 0; j < steps; ++j)
        s += p0[(size_t)j * stride];

    // reduce tp within wave: wave w holds tp in {4w..4w+3}
    s += __shfl_down(s, 32);
    s += __shfl_down(s, 16);
    if ((t & 63) < 16) sm[t >> 6][kk] = s;   // lane tp==4w writes wave-group sum
    __syncthreads();

    if (t < 16) {
        float tot = (sm[0][t] + sm[1][t]) + (sm[2][t] + sm[3][t]);
        tot *= scale;
        float sq = tot * tot;
        float v = tot * (sq / ((1.f + sq) * sqrtf(sq + EPS_)));
        int ko = blockIdx.x * 16 + t;         // = b*160 + n*16 + d natural layout
        if (mode == 0)      Vc[ko] = v;       // after iter 0: Vc = v0
        else if (mode == 1) Vc[ko] += v;      // after iter 1: Vc = v0 + v1
        else                out[ko] = v;      // final output [B,N,1,D]
    }
}

extern "C" void kernel_launch(void* const* d_in, const int* in_sizes, int n_in,
                              void* d_out, int out_size, void* d_ws, size_t ws_size,
                              hipStream_t stream)
{
    const float* x = (const float*)d_in[0];   // [64, 4096, 8] f32
    const float* W = (const float*)d_in[1];   // [4096, 10, 8, 16] f32
    float* out = (float*)d_out;               // [64, 10, 1, 16] f32

    // rows = pass grid size = partial width. Prefer 1024 (4 blocks/CU);
    // fall back to 512 (round-2-proven footprint) if ws is small.
    size_t need1024 = ((size_t)1024 * BND_ + BND_) * sizeof(float);
    int rows = (ws_size >= need1024) ? 1024 : 512;

    float* part = (float*)d_ws;
    float* Vc   = part + (size_t)rows * BND_;

    dim3 blk(256), grid(rows), rgrid(BND_ / 16);

    for (int pass = 0; pass < 3; ++pass) {
        if (rows == 1024) {
            if (pass == 0)
                digitcaps_pass<0, 4><<<grid, blk, 0, stream>>>(x, W, nullptr, part);
            else
                digitcaps_pass<1, 4><<<grid, blk, 0, stream>>>(x, W, Vc, part);
        } else {
            if (pass == 0)
                digitcaps_pass<0, 8><<<grid, blk, 0, stream>>>(x, W, nullptr, part);
            else
                digitcaps_pass<1, 8><<<grid, blk, 0, stream>>>(x, W, Vc, part);
        }
        digitcaps_reduce<<<rgrid, blk, 0, stream>>>(part, rows,
                                                    pass == 0 ? 0.1f : 1.0f, pass, Vc, out);
    }
}